// Round 7
// baseline (2117.618 us; speedup 1.0000x reference)
//
#include <hip/hip_runtime.h>
#include <hip/hip_bf16.h>

typedef __attribute__((ext_vector_type(8))) short   short8;
typedef __attribute__((ext_vector_type(4))) float   floatx4;
typedef __attribute__((ext_vector_type(4))) unsigned short ushort4v;

#define ICH 256

// ---------------- descriptors ----------------

struct Desc {
    int Wd[5];      // spatial size per scale (H==W)
    int BWd[5];     // tile width per scale
    int nbXd[5];    // x-blocks per scale
    int Moff[5];    // pixel offset of scale in fused act buffer
    int aoff[5];    // anchor offset of scale (9*Moff)
    int bstart[6];  // prefix sum of spatial blocks per scale
};

struct FeatPtrs { const float* f[5]; };

// ---------------- conversion kernels ----------------

// fused feats transpose: per batch n, all scales: [256][M] f32 -> [21824][256] bf16
__global__ __launch_bounds__(256)
void convert_feats_all(FeatPtrs fp, Desc d, __hip_bfloat16* __restrict__ out, int n) {
    __shared__ float t[64][65];
    const int p = blockIdx.x * 64;          // global fused pixel index of this chunk
    int sc = 0;
    while (sc < 4 && p >= d.Moff[sc + 1]) ++sc;
    const int M  = d.Wd[sc] * d.Wd[sc];
    const int p0 = p - d.Moff[sc];
    const float* ib = fp.f[sc] + (size_t)n * ICH * M;
    __hip_bfloat16* ob = out + (size_t)p * ICH;
    const int tid = threadIdx.x;
    const int lo = tid & 63, hi = tid >> 6;
    for (int c0 = 0; c0 < ICH; c0 += 64) {
        #pragma unroll
        for (int r = 0; r < 16; ++r) {
            int ic = hi + 4 * r;
            t[ic][lo] = ib[(size_t)(c0 + ic) * M + p0 + lo];
        }
        __syncthreads();
        #pragma unroll
        for (int r = 0; r < 16; ++r) {
            int pp = hi + 4 * r;
            ob[(size_t)pp * ICH + c0 + lo] = __float2bfloat16(t[lo][pp]);
        }
        __syncthreads();
    }
}

// mid weights: [4][256][256][9] f32 -> [4][9][256][256] bf16
__global__ __launch_bounds__(256)
void convert_wmid(const float* __restrict__ in, __hip_bfloat16* __restrict__ out) {
    int idx = blockIdx.x * 256 + threadIdx.x;   // 4*9*256*256 total
    int ic = idx & 255, r = idx >> 8;
    int oc = r & 255, r2 = r >> 8;              // r2 = l*9+s
    int s = r2 % 9, l = r2 / 9;
    out[idx] = __float2bfloat16(in[(size_t)((l * 256 + oc) * 256 + ic) * 9 + s]);
}

// final weights: [OC][256][9] f32 -> [9][OCpad][256] bf16 (zero-padded)
__global__ __launch_bounds__(256)
void convert_wfin(const float* __restrict__ in, __hip_bfloat16* __restrict__ out,
                  int OC, int OCpad) {
    int idx = blockIdx.x * 256 + threadIdx.x;   // 9*OCpad*256 total
    int ic = idx & 255, r = idx >> 8;
    int oc = r % OCpad, s = r / OCpad;
    float v = 0.0f;
    if (oc < OC) v = in[(size_t)(oc * 256 + ic) * 9 + s];
    out[idx] = __float2bfloat16(v);
}

// ---------------- fused MFMA conv kernel ----------------
// Dispatch geometry (r1-verified, best measured traffic: FETCH 80 MB / WRITE 142 MB):
//   2-D grid: blockIdx.x = spatial tile (0..170, fastest-varying), blockIdx.y = cg.
//   x-fastest => concurrent window = a few COMPLETE cg-slices over all tiles:
//     per XCD only ~2-3 weight slices (<2.7 MB, L2-resident), act streamed once per
//     slice-phase, same-line writers temporally adjacent -> L2 write merge.
//   (r2 tile%176: all 8 slices/XCD -> 1 GB thrash. r5 cg-major bands: readers spread
//    over whole dispatch -> 413/636 MB. r6 tile-major bands: 4.7 MB weights + 6 MB
//    write window > 4 MB L2 -> 425/395 MB. r1 geometry is the measured optimum.)
// cg: mid = {clsLo, clsHi, regLo, regHi}; final = {cls oc-block 0..6, reg}.
// act buffers: bf16 [21824][256] (ic contiguous), scale at pixel offset Moff[sc].
// weights: bf16 [9][OCL][256].
// LDS tiles XOR-swizzled (T2): 16B slot s' = s ^ (row & 7)  (conflicts 3.7e4, r2-verified).
// __launch_bounds__(256,3): occupancy ~30% (r3-verified), VGPR 84, no spill.
template<bool FINAL>
__global__ __launch_bounds__(256, 3)
void conv_fused(Desc d,
                const __hip_bfloat16* __restrict__ srcC,
                const __hip_bfloat16* __restrict__ srcR,
                const __hip_bfloat16* __restrict__ wC,
                const __hip_bfloat16* __restrict__ wR,
                const float* __restrict__ bC,
                const float* __restrict__ bR,
                __hip_bfloat16* __restrict__ dstC,
                __hip_bfloat16* __restrict__ dstR,
                float* __restrict__ foutC,
                float* __restrict__ foutR,
                int OCLc, int OCLr, int OCc, int OCr, int KOUTc, int KOUTr)
{
    constexpr int HTOT = 180;       // BWP*BHP: 18*10 == 10*18 for both tile shapes

    __shared__ short lds_act[HTOT * 64];
    __shared__ short lds_w[128 * 64];

    const int bl = blockIdx.x;      // spatial tile, fastest-varying
    const int cg = blockIdx.y;      // slice-group

    int head, oc0;
    if constexpr (FINAL) {
        head = (cg == 7) ? 1 : 0;
        oc0  = head ? 0 : cg * 128;
    } else {
        head = cg >> 1;
        oc0  = (cg & 1) * 128;
    }

    // resolve scale / tile position
    int sc = 0;
    while (bl >= d.bstart[sc + 1]) ++sc;
    const int rb  = bl - d.bstart[sc];
    const int W   = d.Wd[sc], H = W;
    const int BW  = d.BWd[sc], BH = 128 / BW, BWP = BW + 2;
    const int bwsh = (BW == 16) ? 4 : 3;
    const int nbX = d.nbXd[sc];
    const int by  = rb / nbX, bx = rb - by * nbX;
    const int y0  = by * BH, x0 = bx * BW;

    const __hip_bfloat16* actin = head ? srcR : srcC;
    const __hip_bfloat16* wsrc  = head ? wR : wC;
    const float*          bias  = head ? bR : bC;
    const int             OCL   = head ? OCLr : OCLc;

    const int tid  = threadIdx.x;
    const int lane = tid & 63, wv = tid >> 6;
    const int mw = wv >> 1, nw = wv & 1;
    const int ln = lane & 15, q = lane >> 4;
    const int sub = tid & 7, grp = tid >> 3;    // 0..7, 0..31

    const short* actg = (const short*)actin + (size_t)d.Moff[sc] * ICH;
    const short* wg   = (const short*)wsrc;

    // write-side swizzle: rows are grp+32*it -> row&7 == grp&7 (per-thread const)
    const int wsw = (sub ^ (grp & 7)) * 8;

    // A (weights) read: row = mw*64+16j+ln -> row&7 == ln&7 (per-thread const)
    int rowa[4];
    #pragma unroll
    for (int j = 0; j < 4; ++j)
        rowa[j] = (mw * 64 + 16 * j + ln) * 64;
    int asl[2];
    #pragma unroll
    for (int kk = 0; kk < 2; ++kk)
        asl[kk] = ((q + 4 * kk) ^ (ln & 7)) * 8;

    // B (act) read: halo-row index (swizzle applied per-tap since row shifts)
    int prow[4];
    #pragma unroll
    for (int i = 0; i < 4; ++i) {
        int t  = nw * 64 + 16 * i + ln;
        int ty = t >> bwsh, tx = t & (BW - 1);
        prow[i] = (ty + 1) * BWP + tx + 1;
    }

    floatx4 acc[4][4] = {};

    short8 wreg[4];
    auto loadw = [&](int s, int icb) {
        #pragma unroll
        for (int it = 0; it < 4; ++it) {
            int ocl = grp + 32 * it;
            wreg[it] = *(const short8*)(wg + ((size_t)(s * OCL + oc0 + ocl) * ICH
                                              + icb * 64 + sub * 8));
        }
    };

    loadw(0, 0);

    for (int icb = 0; icb < 4; ++icb) {
        // stage activation halo tile (180 px x 64 ic) for this channel block
        #pragma unroll
        for (int it = 0; it < 6; ++it) {
            int hp = grp + 32 * it;
            if (hp < HTOT) {
                int hy = hp / BWP, hx = hp - hy * BWP;
                int gy = y0 - 1 + hy, gx = x0 - 1 + hx;
                short8 v = {};
                if ((unsigned)gy < (unsigned)H && (unsigned)gx < (unsigned)W)
                    v = *(const short8*)(actg + ((size_t)(gy * W + gx) * ICH
                                                 + icb * 64 + sub * 8));
                *(short8*)(&lds_act[hp * 64 + wsw]) = v;
            }
        }
        #pragma unroll
        for (int s = 0; s < 9; ++s) {
            // write prefetched weight tile to LDS (swizzled slot)
            #pragma unroll
            for (int it = 0; it < 4; ++it)
                *(short8*)(&lds_w[(grp + 32 * it) * 64 + wsw]) = wreg[it];
            __syncthreads();
            // prefetch next weight tile (overlaps with MFMA below)
            if (s < 8)          loadw(s + 1, icb);
            else if (icb < 3)   loadw(0, icb + 1);

            const int dy = s / 3 - 1, dx = s % 3 - 1;
            const int dR = dy * BWP + dx;
            #pragma unroll
            for (int kk = 0; kk < 2; ++kk) {
                short8 af[4], bf[4];
                #pragma unroll
                for (int j = 0; j < 4; ++j)
                    af[j] = *(const short8*)(&lds_w[rowa[j] + asl[kk]]);
                #pragma unroll
                for (int i = 0; i < 4; ++i) {
                    int rr = prow[i] + dR;
                    bf[i] = *(const short8*)(
                        &lds_act[rr * 64 + (((q + 4 * kk) ^ (rr & 7)) << 3)]);
                }
                #pragma unroll
                for (int j = 0; j < 4; ++j)
                    #pragma unroll
                    for (int i = 0; i < 4; ++i)
                        acc[j][i] = __builtin_amdgcn_mfma_f32_16x16x32_bf16(
                            af[j], bf[i], acc[j][i], 0, 0, 0);
            }
            __syncthreads();
        }
    }

    // ---------------- epilogue ----------------
    if constexpr (!FINAL) {
        __hip_bfloat16* ob = (head ? dstR : dstC) + (size_t)d.Moff[sc] * ICH;
        #pragma unroll
        for (int j = 0; j < 4; ++j) {
            int oc = oc0 + mw * 64 + 16 * j + q * 4;
            float bv[4];
            #pragma unroll
            for (int r = 0; r < 4; ++r) bv[r] = bias[oc + r];
            #pragma unroll
            for (int i = 0; i < 4; ++i) {
                int t  = nw * 64 + 16 * i + ln;
                int ty = t >> bwsh, tx = t & (BW - 1);
                int gy = y0 + ty;
                if (gy < H) {
                    union { ushort4v v; __hip_bfloat16 h[4]; } u;
                    #pragma unroll
                    for (int r = 0; r < 4; ++r)
                        u.h[r] = __float2bfloat16(fmaxf(acc[j][i][r] + bv[r], 0.0f));
                    *(ushort4v*)(ob + (size_t)(gy * W + x0 + tx) * ICH + oc) = u.v;
                }
            }
        }
    } else {
        const int KOUT = head ? KOUTr : KOUTc;
        const int OC   = head ? OCr : OCc;
        float* fb      = head ? foutR : foutC;
        const int aoff = d.aoff[sc];
        #pragma unroll
        for (int j = 0; j < 4; ++j) {
            int ocb = oc0 + mw * 64 + 16 * j + q * 4;
            #pragma unroll
            for (int i = 0; i < 4; ++i) {
                int t  = nw * 64 + 16 * i + ln;
                int ty = t >> bwsh, tx = t & (BW - 1);
                int gy = y0 + ty;
                if (gy < H) {
                    int p = gy * W + x0 + tx;
                    // (aoff + p*9 + a)*KOUT + c == (aoff + p*9)*KOUT + oc  (contiguous in oc)
                    float* pb = fb + (size_t)(aoff + p * 9) * KOUT;
                    #pragma unroll
                    for (int r = 0; r < 4; ++r) {
                        int oc = ocb + r;
                        if (oc < OC)
                            pb[oc] = acc[j][i][r] + bias[oc];   // normal store: L2 merges
                    }
                }
            }
        }
    }
}

// ---------------- host ----------------

extern "C" void kernel_launch(void* const* d_in, const int* in_sizes, int n_in,
                              void* d_out, int out_size, void* d_ws, size_t ws_size,
                              hipStream_t stream) {
    const float* feats[5];
    for (int i = 0; i < 5; i++) feats[i] = (const float*)d_in[i];
    const float* cls_conv_w = (const float*)d_in[5];
    const float* cls_conv_b = (const float*)d_in[6];
    const float* cls_out_w  = (const float*)d_in[7];
    const float* cls_out_b  = (const float*)d_in[8];
    const float* reg_conv_w = (const float*)d_in[9];
    const float* reg_conv_b = (const float*)d_in[10];
    const float* reg_out_w  = (const float*)d_in[11];
    const float* reg_out_b  = (const float*)d_in[12];

    const int MTOT = 21824;            // sum of H*W over scales
    const int ATOT = 196416;           // 9*MTOT

    // workspace layout (58.85 MB total)
    char* wp = (char*)d_ws;
    const size_t ABUF = (size_t)MTOT * ICH * 2;    // 11,173,888 B per act buffer
    __hip_bfloat16* featC = (__hip_bfloat16*)wp; wp += ABUF;
    __hip_bfloat16* actA0 = (__hip_bfloat16*)wp; wp += ABUF;
    __hip_bfloat16* actB0 = (__hip_bfloat16*)wp; wp += ABUF;
    __hip_bfloat16* actA1 = (__hip_bfloat16*)wp; wp += ABUF;
    __hip_bfloat16* wmid0 = (__hip_bfloat16*)wp; wp += (size_t)4 * 9 * 256 * 256 * 2;
    __hip_bfloat16* wmid1 = (__hip_bfloat16*)wp; wp += (size_t)4 * 9 * 256 * 256 * 2;
    __hip_bfloat16* wfc   = (__hip_bfloat16*)wp; wp += (size_t)9 * 896 * 256 * 2;
    __hip_bfloat16* wfr   = (__hip_bfloat16*)wp; wp += (size_t)9 * 128 * 256 * 2;

    // one-time weight conversions
    convert_wmid<<<4 * 9 * 256, 256, 0, stream>>>(cls_conv_w, wmid0);
    convert_wmid<<<4 * 9 * 256, 256, 0, stream>>>(reg_conv_w, wmid1);
    convert_wfin<<<9 * 896, 256, 0, stream>>>(cls_out_w, wfc, 819, 896);
    convert_wfin<<<9 * 128, 256, 0, stream>>>(reg_out_w, wfr, 36, 128);

    static const Desc d = {
        {128, 64, 32, 16, 8},                   // Wd
        {16, 16, 16, 16, 8},                    // BWd
        {8, 4, 2, 1, 1},                        // nbXd
        {0, 16384, 20480, 21504, 21760},        // Moff
        {0, 147456, 184320, 193536, 195840},    // aoff
        {0, 128, 160, 168, 170, 171}            // bstart
    };
    const int NBLK = 171;

    FeatPtrs fp;
    for (int i = 0; i < 5; i++) fp.f[i] = feats[i];

    float* cls_out = (float*)d_out;
    float* reg_out = (float*)d_out + (size_t)2 * ATOT * 91;

    // activation chains per batch element:
    //   cls: featC -> A0 -> B0 -> A0 -> B0 -> final
    //   reg: featC -> A1 -> featC -> A1 -> featC -> final
    const __hip_bfloat16* srcsC[4] = { featC, actA0, actB0, actA0 };
    __hip_bfloat16*       dstsC[4] = { actA0, actB0, actA0, actB0 };
    const __hip_bfloat16* srcsR[4] = { featC, actA1, featC, actA1 };
    __hip_bfloat16*       dstsR[4] = { actA1, featC, actA1, featC };

    for (int n = 0; n < 2; ++n) {
        convert_feats_all<<<dim3(MTOT / 64), 256, 0, stream>>>(fp, d, featC, n);

        for (int l = 0; l < 4; ++l) {
            conv_fused<false><<<dim3(NBLK, 4), 256, 0, stream>>>(
                d, srcsC[l], srcsR[l],
                wmid0 + (size_t)l * 9 * 256 * 256, wmid1 + (size_t)l * 9 * 256 * 256,
                cls_conv_b + l * 256, reg_conv_b + l * 256,
                dstsC[l], dstsR[l], nullptr, nullptr,
                256, 256, 256, 256, 1, 1);
        }

        conv_fused<true><<<dim3(NBLK, 8), 256, 0, stream>>>(
            d, actB0, featC,
            wfc, wfr, cls_out_b, reg_out_b,
            nullptr, nullptr,
            cls_out + (size_t)n * ATOT * 91, reg_out + (size_t)n * ATOT * 4,
            896, 128, 819, 36, 91, 4);
    }
}

// Round 9
// 1648.661 us; speedup vs baseline: 1.2844x; 1.2844x over previous
//
#include <hip/hip_runtime.h>
#include <hip/hip_bf16.h>

typedef __attribute__((ext_vector_type(8))) short   short8;
typedef __attribute__((ext_vector_type(4))) float   floatx4;
typedef __attribute__((ext_vector_type(4))) unsigned short ushort4v;

#define ICH 256

// ---------------- descriptors ----------------

struct Desc {
    int Wd[5];      // spatial size per scale (H==W)
    int BWd[5];     // tile width per scale
    int nbXd[5];    // x-blocks per scale
    int Moff[5];    // pixel offset of scale in fused act buffer
    int aoff[5];    // anchor offset of scale (9*Moff)
    int bstart[6];  // prefix sum of spatial blocks per scale
};

struct FeatPtrs { const float* f[5]; };

// ---------------- conversion kernels ----------------

// fused feats transpose: per batch n, all scales: [256][M] f32 -> [21824][256] bf16
__global__ __launch_bounds__(256)
void convert_feats_all(FeatPtrs fp, Desc d, __hip_bfloat16* __restrict__ out, int n) {
    __shared__ float t[64][65];
    const int p = blockIdx.x * 64;          // global fused pixel index of this chunk
    int sc = 0;
    while (sc < 4 && p >= d.Moff[sc + 1]) ++sc;
    const int M  = d.Wd[sc] * d.Wd[sc];
    const int p0 = p - d.Moff[sc];
    const float* ib = fp.f[sc] + (size_t)n * ICH * M;
    __hip_bfloat16* ob = out + (size_t)p * ICH;
    const int tid = threadIdx.x;
    const int lo = tid & 63, hi = tid >> 6;
    for (int c0 = 0; c0 < ICH; c0 += 64) {
        #pragma unroll
        for (int r = 0; r < 16; ++r) {
            int ic = hi + 4 * r;
            t[ic][lo] = ib[(size_t)(c0 + ic) * M + p0 + lo];
        }
        __syncthreads();
        #pragma unroll
        for (int r = 0; r < 16; ++r) {
            int pp = hi + 4 * r;
            ob[(size_t)pp * ICH + c0 + lo] = __float2bfloat16(t[lo][pp]);
        }
        __syncthreads();
    }
}

// mid weights: [4][256][256][9] f32 -> [4][9][256][256] bf16
__global__ __launch_bounds__(256)
void convert_wmid(const float* __restrict__ in, __hip_bfloat16* __restrict__ out) {
    int idx = blockIdx.x * 256 + threadIdx.x;   // 4*9*256*256 total
    int ic = idx & 255, r = idx >> 8;
    int oc = r & 255, r2 = r >> 8;              // r2 = l*9+s
    int s = r2 % 9, l = r2 / 9;
    out[idx] = __float2bfloat16(in[(size_t)((l * 256 + oc) * 256 + ic) * 9 + s]);
}

// final weights: [OC][256][9] f32 -> [9][OCpad][256] bf16 (zero-padded)
__global__ __launch_bounds__(256)
void convert_wfin(const float* __restrict__ in, __hip_bfloat16* __restrict__ out,
                  int OC, int OCpad) {
    int idx = blockIdx.x * 256 + threadIdx.x;   // 9*OCpad*256 total
    int ic = idx & 255, r = idx >> 8;
    int oc = r % OCpad, s = r / OCpad;
    float v = 0.0f;
    if (oc < OC) v = in[(size_t)(oc * 256 + ic) * 9 + s];
    out[idx] = __float2bfloat16(v);
}

// ---------------- fused MFMA conv kernel ----------------
// Dispatch geometry (r1-verified best traffic: FETCH 80 / WRITE 142 MB):
//   2-D grid: blockIdx.x = spatial tile (fastest), blockIdx.y = cg slice-group.
// OCCUPANCY/VGPR (r1-r7 spill forensics):
//   live state ~130-150 VGPRs. launch_bounds(256,3)/(256,4) capped VGPR at 84/64
//   -> scratch spills -> +600 MB symmetric HBM traffic/dispatch, drowning every
//   scheduling change (r3-r7 all ~850 MB, MfmaUtil ~12%, VALUBusy ~7%).
//   (256,2) = VGPR 128, NO spills (r1: 222 MB total, MfmaUtil 18%). KEEP AT 2.
// cg: mid = {clsLo, clsHi, regLo, regHi}; final = {cls oc-block 0..6, reg}.
// act buffers: bf16 [21824][256] (ic contiguous), scale at pixel offset Moff[sc].
// weights: bf16 [9][OCL][256].
// LDS tiles XOR-swizzled (T2): 16B slot s' = s ^ (row & 7) (conflicts 3.78e7->3.7e4, r2).
template<bool FINAL>
__global__ __launch_bounds__(256, 2)
void conv_fused(Desc d,
                const __hip_bfloat16* __restrict__ srcC,
                const __hip_bfloat16* __restrict__ srcR,
                const __hip_bfloat16* __restrict__ wC,
                const __hip_bfloat16* __restrict__ wR,
                const float* __restrict__ bC,
                const float* __restrict__ bR,
                __hip_bfloat16* __restrict__ dstC,
                __hip_bfloat16* __restrict__ dstR,
                float* __restrict__ foutC,
                float* __restrict__ foutR,
                int OCLc, int OCLr, int OCc, int OCr, int KOUTc, int KOUTr)
{
    constexpr int HTOT = 180;       // BWP*BHP: 18*10 == 10*18 for both tile shapes

    __shared__ short lds_act[HTOT * 64];
    __shared__ short lds_w[128 * 64];

    const int bl = blockIdx.x;      // spatial tile, fastest-varying
    const int cg = blockIdx.y;      // slice-group

    int head, oc0;
    if constexpr (FINAL) {
        head = (cg == 7) ? 1 : 0;
        oc0  = head ? 0 : cg * 128;
    } else {
        head = cg >> 1;
        oc0  = (cg & 1) * 128;
    }

    // resolve scale / tile position
    int sc = 0;
    while (bl >= d.bstart[sc + 1]) ++sc;
    const int rb  = bl - d.bstart[sc];
    const int W   = d.Wd[sc], H = W;
    const int BW  = d.BWd[sc], BH = 128 / BW, BWP = BW + 2;
    const int bwsh = (BW == 16) ? 4 : 3;
    const int nbX = d.nbXd[sc];
    const int by  = rb / nbX, bx = rb - by * nbX;
    const int y0  = by * BH, x0 = bx * BW;

    const __hip_bfloat16* actin = head ? srcR : srcC;
    const __hip_bfloat16* wsrc  = head ? wR : wC;
    const float*          bias  = head ? bR : bC;
    const int             OCL   = head ? OCLr : OCLc;

    const int tid  = threadIdx.x;
    const int lane = tid & 63, wv = tid >> 6;
    const int mw = wv >> 1, nw = wv & 1;
    const int ln = lane & 15, q = lane >> 4;
    const int sub = tid & 7, grp = tid >> 3;    // 0..7, 0..31

    const short* actg = (const short*)actin + (size_t)d.Moff[sc] * ICH;
    const short* wg   = (const short*)wsrc;

    // write-side swizzle: rows are grp+32*it -> row&7 == grp&7 (per-thread const)
    const int wsw = (sub ^ (grp & 7)) * 8;

    // A (weights) read: row = mw*64+16j+ln -> row&7 == ln&7 (per-thread const)
    int rowa[4];
    #pragma unroll
    for (int j = 0; j < 4; ++j)
        rowa[j] = (mw * 64 + 16 * j + ln) * 64;
    int asl[2];
    #pragma unroll
    for (int kk = 0; kk < 2; ++kk)
        asl[kk] = ((q + 4 * kk) ^ (ln & 7)) * 8;

    // B (act) read: halo-row index (swizzle applied per-tap since row shifts)
    int prow[4];
    #pragma unroll
    for (int i = 0; i < 4; ++i) {
        int t  = nw * 64 + 16 * i + ln;
        int ty = t >> bwsh, tx = t & (BW - 1);
        prow[i] = (ty + 1) * BWP + tx + 1;
    }

    floatx4 acc[4][4] = {};

    short8 wreg[4];
    auto loadw = [&](int s, int icb) {
        #pragma unroll
        for (int it = 0; it < 4; ++it) {
            int ocl = grp + 32 * it;
            wreg[it] = *(const short8*)(wg + ((size_t)(s * OCL + oc0 + ocl) * ICH
                                              + icb * 64 + sub * 8));
        }
    };

    loadw(0, 0);

    for (int icb = 0; icb < 4; ++icb) {
        // stage activation halo tile (180 px x 64 ic) for this channel block
        #pragma unroll
        for (int it = 0; it < 6; ++it) {
            int hp = grp + 32 * it;
            if (hp < HTOT) {
                int hy = hp / BWP, hx = hp - hy * BWP;
                int gy = y0 - 1 + hy, gx = x0 - 1 + hx;
                short8 v = {};
                if ((unsigned)gy < (unsigned)H && (unsigned)gx < (unsigned)W)
                    v = *(const short8*)(actg + ((size_t)(gy * W + gx) * ICH
                                                 + icb * 64 + sub * 8));
                *(short8*)(&lds_act[hp * 64 + wsw]) = v;
            }
        }
        #pragma unroll
        for (int s = 0; s < 9; ++s) {
            // write prefetched weight tile to LDS (swizzled slot)
            #pragma unroll
            for (int it = 0; it < 4; ++it)
                *(short8*)(&lds_w[(grp + 32 * it) * 64 + wsw]) = wreg[it];
            __syncthreads();
            // prefetch next weight tile (overlaps with MFMA below)
            if (s < 8)          loadw(s + 1, icb);
            else if (icb < 3)   loadw(0, icb + 1);

            const int dy = s / 3 - 1, dx = s % 3 - 1;
            const int dR = dy * BWP + dx;
            #pragma unroll
            for (int kk = 0; kk < 2; ++kk) {
                short8 af[4], bf[4];
                #pragma unroll
                for (int j = 0; j < 4; ++j)
                    af[j] = *(const short8*)(&lds_w[rowa[j] + asl[kk]]);
                #pragma unroll
                for (int i = 0; i < 4; ++i) {
                    int rr = prow[i] + dR;
                    bf[i] = *(const short8*)(
                        &lds_act[rr * 64 + (((q + 4 * kk) ^ (rr & 7)) << 3)]);
                }
                #pragma unroll
                for (int j = 0; j < 4; ++j)
                    #pragma unroll
                    for (int i = 0; i < 4; ++i)
                        acc[j][i] = __builtin_amdgcn_mfma_f32_16x16x32_bf16(
                            af[j], bf[i], acc[j][i], 0, 0, 0);
            }
            __syncthreads();
        }
    }

    // ---------------- epilogue ----------------
    if constexpr (!FINAL) {
        __hip_bfloat16* ob = (head ? dstR : dstC) + (size_t)d.Moff[sc] * ICH;
        #pragma unroll
        for (int j = 0; j < 4; ++j) {
            int oc = oc0 + mw * 64 + 16 * j + q * 4;
            float bv[4];
            #pragma unroll
            for (int r = 0; r < 4; ++r) bv[r] = bias[oc + r];
            #pragma unroll
            for (int i = 0; i < 4; ++i) {
                int t  = nw * 64 + 16 * i + ln;
                int ty = t >> bwsh, tx = t & (BW - 1);
                int gy = y0 + ty;
                if (gy < H) {
                    union { ushort4v v; __hip_bfloat16 h[4]; } u;
                    #pragma unroll
                    for (int r = 0; r < 4; ++r)
                        u.h[r] = __float2bfloat16(fmaxf(acc[j][i][r] + bv[r], 0.0f));
                    *(ushort4v*)(ob + (size_t)(gy * W + x0 + tx) * ICH + oc) = u.v;
                }
            }
        }
    } else {
        const int KOUT = head ? KOUTr : KOUTc;
        const int OC   = head ? OCr : OCc;
        float* fb      = head ? foutR : foutC;
        const int aoff = d.aoff[sc];
        #pragma unroll
        for (int j = 0; j < 4; ++j) {
            int ocb = oc0 + mw * 64 + 16 * j + q * 4;
            #pragma unroll
            for (int i = 0; i < 4; ++i) {
                int t  = nw * 64 + 16 * i + ln;
                int ty = t >> bwsh, tx = t & (BW - 1);
                int gy = y0 + ty;
                if (gy < H) {
                    int p = gy * W + x0 + tx;
                    // (aoff + p*9 + a)*KOUT + c == (aoff + p*9)*KOUT + oc  (contiguous in oc)
                    float* pb = fb + (size_t)(aoff + p * 9) * KOUT;
                    #pragma unroll
                    for (int r = 0; r < 4; ++r) {
                        int oc = ocb + r;
                        if (oc < OC)
                            pb[oc] = acc[j][i][r] + bias[oc];   // normal store: L2 merges
                    }
                }
            }
        }
    }
}

// ---------------- host ----------------

extern "C" void kernel_launch(void* const* d_in, const int* in_sizes, int n_in,
                              void* d_out, int out_size, void* d_ws, size_t ws_size,
                              hipStream_t stream) {
    const float* feats[5];
    for (int i = 0; i < 5; i++) feats[i] = (const float*)d_in[i];
    const float* cls_conv_w = (const float*)d_in[5];
    const float* cls_conv_b = (const float*)d_in[6];
    const float* cls_out_w  = (const float*)d_in[7];
    const float* cls_out_b  = (const float*)d_in[8];
    const float* reg_conv_w = (const float*)d_in[9];
    const float* reg_conv_b = (const float*)d_in[10];
    const float* reg_out_w  = (const float*)d_in[11];
    const float* reg_out_b  = (const float*)d_in[12];

    const int MTOT = 21824;            // sum of H*W over scales
    const int ATOT = 196416;           // 9*MTOT

    // workspace layout (58.85 MB total)
    char* wp = (char*)d_ws;
    const size_t ABUF = (size_t)MTOT * ICH * 2;    // 11,173,888 B per act buffer
    __hip_bfloat16* featC = (__hip_bfloat16*)wp; wp += ABUF;
    __hip_bfloat16* actA0 = (__hip_bfloat16*)wp; wp += ABUF;
    __hip_bfloat16* actB0 = (__hip_bfloat16*)wp; wp += ABUF;
    __hip_bfloat16* actA1 = (__hip_bfloat16*)wp; wp += ABUF;
    __hip_bfloat16* wmid0 = (__hip_bfloat16*)wp; wp += (size_t)4 * 9 * 256 * 256 * 2;
    __hip_bfloat16* wmid1 = (__hip_bfloat16*)wp; wp += (size_t)4 * 9 * 256 * 256 * 2;
    __hip_bfloat16* wfc   = (__hip_bfloat16*)wp; wp += (size_t)9 * 896 * 256 * 2;
    __hip_bfloat16* wfr   = (__hip_bfloat16*)wp; wp += (size_t)9 * 128 * 256 * 2;

    // one-time weight conversions
    convert_wmid<<<4 * 9 * 256, 256, 0, stream>>>(cls_conv_w, wmid0);
    convert_wmid<<<4 * 9 * 256, 256, 0, stream>>>(reg_conv_w, wmid1);
    convert_wfin<<<9 * 896, 256, 0, stream>>>(cls_out_w, wfc, 819, 896);
    convert_wfin<<<9 * 128, 256, 0, stream>>>(reg_out_w, wfr, 36, 128);

    static const Desc d = {
        {128, 64, 32, 16, 8},                   // Wd
        {16, 16, 16, 16, 8},                    // BWd
        {8, 4, 2, 1, 1},                        // nbXd
        {0, 16384, 20480, 21504, 21760},        // Moff
        {0, 147456, 184320, 193536, 195840},    // aoff
        {0, 128, 160, 168, 170, 171}            // bstart
    };
    const int NBLK = 171;

    FeatPtrs fp;
    for (int i = 0; i < 5; i++) fp.f[i] = feats[i];

    float* cls_out = (float*)d_out;
    float* reg_out = (float*)d_out + (size_t)2 * ATOT * 91;

    // activation chains per batch element:
    //   cls: featC -> A0 -> B0 -> A0 -> B0 -> final
    //   reg: featC -> A1 -> featC -> A1 -> featC -> final
    const __hip_bfloat16* srcsC[4] = { featC, actA0, actB0, actA0 };
    __hip_bfloat16*       dstsC[4] = { actA0, actB0, actA0, actB0 };
    const __hip_bfloat16* srcsR[4] = { featC, actA1, featC, actA1 };
    __hip_bfloat16*       dstsR[4] = { actA1, featC, actA1, featC };

    for (int n = 0; n < 2; ++n) {
        convert_feats_all<<<dim3(MTOT / 64), 256, 0, stream>>>(fp, d, featC, n);

        for (int l = 0; l < 4; ++l) {
            conv_fused<false><<<dim3(NBLK, 4), 256, 0, stream>>>(
                d, srcsC[l], srcsR[l],
                wmid0 + (size_t)l * 9 * 256 * 256, wmid1 + (size_t)l * 9 * 256 * 256,
                cls_conv_b + l * 256, reg_conv_b + l * 256,
                dstsC[l], dstsR[l], nullptr, nullptr,
                256, 256, 256, 256, 1, 1);
        }

        conv_fused<true><<<dim3(NBLK, 8), 256, 0, stream>>>(
            d, actB0, featC,
            wfc, wfr, cls_out_b, reg_out_b,
            nullptr, nullptr,
            cls_out + (size_t)n * ATOT * 91, reg_out + (size_t)n * ATOT * 4,
            896, 128, 819, 36, 91, 4);
    }
}